// Round 4
// baseline (392.544 us; speedup 1.0000x reference)
//
#include <hip/hip_runtime.h>
#include <hip/hip_bf16.h>
#include <stdint.h>

// Problem constants (from reference setup_inputs)
#define N_TOK 4096
#define DIM   1024
#define NE    8
#define NH    2048
#define NO    1024

typedef __attribute__((ext_vector_type(8))) short bf16x8;
typedef __attribute__((ext_vector_type(16))) float f32x16;

__device__ inline unsigned short f2bf(float f) {
    unsigned u = __float_as_uint(f);
    u += 0x7fffu + ((u >> 16) & 1u);   // round-to-nearest-even
    return (unsigned short)(u >> 16);
}

__device__ inline void async_copy16(const void* g, void* l) {
    __builtin_amdgcn_global_load_lds(
        (const __attribute__((address_space(1))) void*)g,
        (__attribute__((address_space(3))) void*)l, 16, 0, 0);
}

__device__ inline bf16x8 pack_bf8(float4 a, float4 b) {
    bf16x8 o;
    o[0] = (short)f2bf(a.x); o[1] = (short)f2bf(a.y);
    o[2] = (short)f2bf(a.z); o[3] = (short)f2bf(a.w);
    o[4] = (short)f2bf(b.x); o[5] = (short)f2bf(b.y);
    o[6] = (short)f2bf(b.z); o[7] = (short)f2bf(b.w);
    return o;
}

// ---------------- prep: layernorm + gating only ----------------
// One block (256 thr) per token row. Expert weights are NOT converted any
// more -- gemm1/gemm2 read fp32 weights directly and convert during LDS
// staging (saves the 134 MB fp32 read + 67 MB bf16 write round-trip).
__global__ __launch_bounds__(256) void ln_gate_kernel(
    const float* __restrict__ x, const float* __restrict__ nw,
    const float* __restrict__ nb, const float* __restrict__ eps_p,
    const float* __restrict__ wg,
    unsigned short* __restrict__ xn_bf, unsigned short* __restrict__ x_bf,
    int* __restrict__ tok_e, float* __restrict__ tok_g)
{
    __shared__ float rs[4], rs2[4];
    __shared__ float gred[4][NE];

    int n = blockIdx.x, t = threadIdx.x;
    int lane = t & 63, wv = t >> 6;

    const float4 xv = ((const float4*)(x + (size_t)n * DIM))[t];
    float s  = xv.x + xv.y + xv.z + xv.w;
    float s2 = xv.x*xv.x + xv.y*xv.y + xv.z*xv.z + xv.w*xv.w;
    #pragma unroll
    for (int o = 32; o > 0; o >>= 1) {
        s  += __shfl_down(s, o);
        s2 += __shfl_down(s2, o);
    }
    if (lane == 0) { rs[wv] = s; rs2[wv] = s2; }
    __syncthreads();
    float S  = rs[0] + rs[1] + rs[2] + rs[3];
    float S2 = rs2[0] + rs2[1] + rs2[2] + rs2[3];
    const float inv = 1.0f / (float)DIM;
    float mu = S * inv;
    float var = fmaxf(S2 * inv - mu * mu, 0.0f);   // biased, like F.layer_norm
    float rstd = rsqrtf(var + eps_p[0]);

    float4 w4 = ((const float4*)nw)[t];
    float4 b4 = ((const float4*)nb)[t];
    float xn0 = (xv.x - mu) * rstd * w4.x + b4.x;
    float xn1 = (xv.y - mu) * rstd * w4.y + b4.y;
    float xn2 = (xv.z - mu) * rstd * w4.z + b4.z;
    float xn3 = (xv.w - mu) * rstd * w4.w + b4.w;

    ushort4 pn; pn.x = f2bf(xn0); pn.y = f2bf(xn1); pn.z = f2bf(xn2); pn.w = f2bf(xn3);
    ((ushort4*)(xn_bf + (size_t)n * DIM))[t] = pn;
    ushort4 px; px.x = f2bf(xv.x); px.y = f2bf(xv.y); px.z = f2bf(xv.z); px.w = f2bf(xv.w);
    ((ushort4*)(x_bf + (size_t)n * DIM))[t] = px;

    // gating logits: x_norm (fp32) @ w_gate [D][E]
    float acc[NE];
    #pragma unroll
    for (int e = 0; e < NE; ++e) acc[e] = 0.0f;
    float xns[4] = {xn0, xn1, xn2, xn3};
    const float4* wgp = (const float4*)(wg + (size_t)(4 * t) * NE);
    #pragma unroll
    for (int j = 0; j < 4; ++j) {
        float4 w0 = wgp[2 * j], w1 = wgp[2 * j + 1];
        float xj = xns[j];
        acc[0] += xj * w0.x; acc[1] += xj * w0.y; acc[2] += xj * w0.z; acc[3] += xj * w0.w;
        acc[4] += xj * w1.x; acc[5] += xj * w1.y; acc[6] += xj * w1.z; acc[7] += xj * w1.w;
    }
    #pragma unroll
    for (int o = 32; o > 0; o >>= 1) {
        #pragma unroll
        for (int e = 0; e < NE; ++e) acc[e] += __shfl_down(acc[e], o);
    }
    if (lane == 0) {
        #pragma unroll
        for (int e = 0; e < NE; ++e) gred[wv][e] = acc[e];
    }
    __syncthreads();
    if (t == 0) {
        float lg[NE];
        float nrm2 = 0.0f;
        #pragma unroll
        for (int e = 0; e < NE; ++e) {
            lg[e] = gred[0][e] + gred[1][e] + gred[2][e] + gred[3][e];
            nrm2 += lg[e] * lg[e];
        }
        float den = fmaxf(sqrtf(nrm2), 1e-12f);
        float linv = 1.0f / den;
        #pragma unroll
        for (int e = 0; e < NE; ++e) lg[e] *= linv;
        float mx = lg[0];
        #pragma unroll
        for (int e = 1; e < NE; ++e) mx = fmaxf(mx, lg[e]);
        float p[NE], ps = 0.0f;
        #pragma unroll
        for (int e = 0; e < NE; ++e) { p[e] = expf(lg[e] - mx); ps += p[e]; }
        float pinv = 1.0f / ps;
        #pragma unroll
        for (int e = 0; e < NE; ++e) p[e] *= pinv;
        // top-2, lowest-index wins ties (jax.lax.top_k semantics)
        int i0 = 0; float b0 = lg[0];
        #pragma unroll
        for (int e = 1; e < NE; ++e) if (lg[e] > b0) { b0 = lg[e]; i0 = e; }
        int i1 = -1; float b1 = -3.0e38f;
        #pragma unroll
        for (int e = 0; e < NE; ++e) if (e != i0 && lg[e] > b1) { b1 = lg[e]; i1 = e; }
        tok_e[2 * n] = i0; tok_e[2 * n + 1] = i1;
        tok_g[2 * n] = p[i0]; tok_g[2 * n + 1] = p[i1];
    }
}

// ---------------- loss helper ----------------
__device__ inline float cv_sq(const float* v) {
    float m = 0.0f;
    for (int e = 0; e < NE; ++e) m += v[e];
    m *= (1.0f / NE);
    float s = 0.0f;
    for (int e = 0; e < NE; ++e) { float d = v[e] - m; s += d * d; }
    s *= (1.0f / (NE - 1));          // ddof=1
    return s / (m * m + 1e-6f);
}

// ---------------- routing + wout transpose ----------------
// blocks 0..7    : routing (histogram/offsets/loss/scatter + invslot)
// blocks 8..1031 : output_weight [D][O] -> bf16 [O][D], 32x32 tiles
__global__ __launch_bounds__(256) void routing_kernel(
    const int* __restrict__ tok_e, const float* __restrict__ tok_g,
    int* __restrict__ counts, int* __restrict__ offsets,
    int* __restrict__ rowsbuf, int* __restrict__ invslot,
    float* __restrict__ out_tail,
    const float* __restrict__ wout, unsigned short* __restrict__ wt_bf)
{
    __shared__ float tile[32][33];
    __shared__ int   sc[4][NE], sp[4][NE];
    __shared__ float sf[4][NE];
    __shared__ int   lcur[NE];

    int b = blockIdx.x, t = threadIdx.x;

    if (b >= 8) {
        // ---- output_weight transpose+cvt ----
        int idx = b - 8;
        int o0 = (idx & 31) * 32, d0 = (idx >> 5) * 32;
        int tx = t & 31, ty0 = t >> 5;      // 32 x 8 threads, 4 rows each
        #pragma unroll
        for (int k = 0; k < 4; ++k) {
            int ty = ty0 + k * 8;
            tile[ty][tx] = wout[(size_t)(d0 + ty) * NO + o0 + tx];
        }
        __syncthreads();
        #pragma unroll
        for (int k = 0; k < 4; ++k) {
            int ty = ty0 + k * 8;
            wt_bf[(size_t)(o0 + ty) * DIM + d0 + tx] = f2bf(tile[tx][ty]);
        }
        return;
    }

    int rb = b;
    int lane = t & 63, wv = t >> 6;       // 4 waves
    int chunk0 = rb * 1024;

    int lc[NE]; float li[NE];
    #pragma unroll
    for (int e = 0; e < NE; ++e) { lc[e] = 0; li[e] = 0.0f; }
    int base = t * 32;
    #pragma unroll
    for (int q = 0; q < 8; ++q) {
        int4 e4 = *(const int4*)(tok_e + base + q * 4);
        float4 g4 = *(const float4*)(tok_g + base + q * 4);
        lc[e4.x]++; li[e4.x] += g4.x;
        lc[e4.y]++; li[e4.y] += g4.y;
        lc[e4.z]++; li[e4.z] += g4.z;
        lc[e4.w]++; li[e4.w] += g4.w;
    }
    int prior_flag = (base + 32 <= chunk0) ? 1 : 0;   // stripes don't straddle chunks
    int lp[NE];
    #pragma unroll
    for (int e = 0; e < NE; ++e) lp[e] = prior_flag ? lc[e] : 0;

    #pragma unroll
    for (int o = 32; o > 0; o >>= 1) {
        #pragma unroll
        for (int e = 0; e < NE; ++e) {
            lc[e] += __shfl_down(lc[e], o);
            lp[e] += __shfl_down(lp[e], o);
            li[e] += __shfl_down(li[e], o);
        }
    }
    if (lane == 0) {
        #pragma unroll
        for (int e = 0; e < NE; ++e) { sc[wv][e] = lc[e]; sp[wv][e] = lp[e]; sf[wv][e] = li[e]; }
    }
    __syncthreads();
    if (t == 0) {
        int cnt[NE], pri[NE]; float imp[NE];
        for (int e = 0; e < NE; ++e) {
            cnt[e] = sc[0][e] + sc[1][e] + sc[2][e] + sc[3][e];
            pri[e] = sp[0][e] + sp[1][e] + sp[2][e] + sp[3][e];
            imp[e] = sf[0][e] + sf[1][e] + sf[2][e] + sf[3][e];
        }
        int off = 0;
        for (int e = 0; e < NE; ++e) {
            lcur[e] = off + pri[e];
            if (rb == 0) { counts[e] = cnt[e]; offsets[e] = off; }
            off += cnt[e];
        }
        if (rb == 0) {
            float lcf[NE], lif[NE];
            for (int e = 0; e < NE; ++e) { lcf[e] = (float)cnt[e]; lif[e] = imp[e]; }
            float tot = (float)off;
            out_tail[0] = 0.01f * (cv_sq(lif) + cv_sq(lcf));              // loss
            for (int e = 0; e < NE; ++e) out_tail[1 + e] = lcf[e] / tot;  // gate_fraction
        }
    }
    __syncthreads();

    int g0 = chunk0 + 4 * t;
    int4 e4 = *(const int4*)(tok_e + g0);
    int s0 = atomicAdd(&lcur[e4.x], 1);
    int s1 = atomicAdd(&lcur[e4.y], 1);
    int s2 = atomicAdd(&lcur[e4.z], 1);
    int s3 = atomicAdd(&lcur[e4.w], 1);
    int tok0 = g0 >> 1;
    rowsbuf[s0] = tok0;     rowsbuf[s1] = tok0;
    rowsbuf[s2] = tok0 + 1; rowsbuf[s3] = tok0 + 1;
    invslot[g0]     = s0;   invslot[g0 + 1] = s1;
    invslot[g0 + 2] = s2;   invslot[g0 + 3] = s3;
}

// ---------------- GEMM kernels (32x32x16 MFMA) ----------------
// LDS layout: [row][64 shorts]; logical 16B-slot s of row r stored at physical
// slot s ^ (r & 7) -> bank-balanced wave64 ds_read_b128.
// A-panels (bf16 activations): async global_load_lds, source-column swizzled.
// B-panels (fp32 weights): reg-staged -- 2x float4 load at the swizzled column
// group, pack to bf16x8, one ds_write_b128 to the lane-contiguous LDS slot.
// Same LDS image as before; conversion is free under the GEMM's latency.
// Fragments (32x32x16 bf16): A/B lane: row lane&31, k=(lane>>5)*8+j;
// C/D: col=lane&31, row=(reg&3)+8*(reg>>2)+4*(lane>>5)  [m74/m101].
#define BK 64

// GEMM1: 128x128 tile, wave = 2x2 blocks of 32x32.  B = experts_hidden_w fp32.
__global__ __launch_bounds__(256) void gemm1_kernel(
    const unsigned short* __restrict__ xn,   // [N][D] bf16
    const float* __restrict__ wh,            // [E][H][D] fp32
    const float* __restrict__ hb,            // [E][H]
    const int* __restrict__ rowsbuf,
    const int* __restrict__ counts, const int* __restrict__ offsets,
    unsigned short* __restrict__ hbuf)       // [2N][H] bf16
{
    int e = blockIdx.z;
    int count = counts[e];
    int tm = blockIdx.y, tn = blockIdx.x;
    if (tm * 128 >= count) return;
    int off = offsets[e];

    __shared__ alignas(16) short As[128 * BK];
    __shared__ alignas(16) short Bs[128 * BK];

    int t = threadIdx.x;
    int c = t & 7, rl = t >> 3;
    int csw = (c ^ (rl & 7)) * 8;            // swizzled source column (elements)
    const unsigned short* aptr[4];
    const float* bptr[4];
    #pragma unroll
    for (int p = 0; p < 4; ++p) {
        int mrow = tm * 128 + p * 32 + rl;
        int mc = mrow < count ? mrow : count - 1;
        int token = rowsbuf[off + mc];
        aptr[p] = xn + (size_t)token * DIM;
        bptr[p] = wh + ((size_t)e * NH + tn * 128 + p * 32 + rl) * DIM;
    }

    int lane = t & 63, wvi = t >> 6;
    int wm = (wvi & 1) * 64, wn = (wvi >> 1) * 64;
    int l31 = lane & 31, h = lane >> 5, sw = l31 & 7;

    f32x16 acc[2][2];
    #pragma unroll
    for (int i = 0; i < 2; ++i)
        #pragma unroll
        for (int j = 0; j < 2; ++j) acc[i][j] = (f32x16)(0.0f);

    for (int kt = 0; kt < DIM / BK; ++kt) {
        int kb = kt * BK + csw;
        #pragma unroll
        for (int p = 0; p < 4; ++p)
            async_copy16(aptr[p] + kb, (char*)As + p * 4096 + t * 16);
        float4 b0[4], b1[4];
        #pragma unroll
        for (int p = 0; p < 4; ++p) {
            const float4* src = (const float4*)(bptr[p] + kb);
            b0[p] = src[0]; b1[p] = src[1];
        }
        #pragma unroll
        for (int p = 0; p < 4; ++p)
            *(bf16x8*)((char*)Bs + p * 4096 + t * 16) = pack_bf8(b0[p], b1[p]);
        __syncthreads();
        #pragma unroll
        for (int ks = 0; ks < 4; ++ks) {
            int ph = ((ks * 2 + h) ^ sw) * 8;
            bf16x8 af[2], bfr[2];
            #pragma unroll
            for (int i = 0; i < 2; ++i)
                af[i] = *(const bf16x8*)&As[(wm + i * 32 + l31) * BK + ph];
            #pragma unroll
            for (int j = 0; j < 2; ++j)
                bfr[j] = *(const bf16x8*)&Bs[(wn + j * 32 + l31) * BK + ph];
            #pragma unroll
            for (int i = 0; i < 2; ++i)
                #pragma unroll
                for (int j = 0; j < 2; ++j)
                    acc[i][j] = __builtin_amdgcn_mfma_f32_32x32x16_bf16(af[i], bfr[j], acc[i][j], 0, 0, 0);
        }
        __syncthreads();
    }

    #pragma unroll
    for (int i = 0; i < 2; ++i) {
        #pragma unroll
        for (int j = 0; j < 2; ++j) {
            int col = tn * 128 + wn + j * 32 + l31;
            float bias = hb[e * NH + col];
            #pragma unroll
            for (int r = 0; r < 16; ++r) {
                int row_d = (r & 3) + 8 * (r >> 2) + 4 * h;
                int m = tm * 128 + wm + i * 32 + row_d;
                if (m < count) {
                    float v = acc[i][j][r] + bias;
                    v = v / (1.0f + __expf(-v));           // silu
                    hbuf[(size_t)(off + m) * NH + col] = f2bf(v);
                }
            }
        }
    }
}

// GEMM2: 128x128 tile, wave = 2x2 blocks of 32x32.  B = experts_w fp32.
// Epilogue: plain fp32 store of (acc + bias) into eo[slot][col] — NO atomics.
__global__ __launch_bounds__(256) void gemm2_kernel(
    const unsigned short* __restrict__ hbuf,  // [2N][H] bf16
    const float* __restrict__ wo,             // [E][O][H] fp32
    const float* __restrict__ ob,             // [E][O]
    const int* __restrict__ counts, const int* __restrict__ offsets,
    float* __restrict__ eo)                   // [2N][O] fp32, slot-indexed
{
    int e = blockIdx.z;
    int count = counts[e];
    int tm = blockIdx.y, tn = blockIdx.x;
    if (tm * 128 >= count) return;
    int off = offsets[e];

    __shared__ alignas(16) short As[128 * BK];
    __shared__ alignas(16) short Bs[128 * BK];

    int t = threadIdx.x;
    int c = t & 7, rl = t >> 3;
    int csw = (c ^ (rl & 7)) * 8;
    const unsigned short* aptr[4];
    const float* bptr[4];
    #pragma unroll
    for (int p = 0; p < 4; ++p) {
        int mrow = tm * 128 + p * 32 + rl;
        int mc = mrow < count ? mrow : count - 1;
        aptr[p] = hbuf + (size_t)(off + mc) * NH;
        bptr[p] = wo + ((size_t)e * NO + tn * 128 + p * 32 + rl) * NH;
    }

    int lane = t & 63, wvi = t >> 6;
    int wm = (wvi & 1) * 64, wn = (wvi >> 1) * 64;
    int l31 = lane & 31, h = lane >> 5, sw = l31 & 7;

    f32x16 acc[2][2];
    #pragma unroll
    for (int i = 0; i < 2; ++i)
        #pragma unroll
        for (int j = 0; j < 2; ++j) acc[i][j] = (f32x16)(0.0f);

    for (int kt = 0; kt < NH / BK; ++kt) {
        int kb = kt * BK + csw;
        #pragma unroll
        for (int p = 0; p < 4; ++p)
            async_copy16(aptr[p] + kb, (char*)As + p * 4096 + t * 16);
        float4 b0[4], b1[4];
        #pragma unroll
        for (int p = 0; p < 4; ++p) {
            const float4* src = (const float4*)(bptr[p] + kb);
            b0[p] = src[0]; b1[p] = src[1];
        }
        #pragma unroll
        for (int p = 0; p < 4; ++p)
            *(bf16x8*)((char*)Bs + p * 4096 + t * 16) = pack_bf8(b0[p], b1[p]);
        __syncthreads();
        #pragma unroll
        for (int ks = 0; ks < 4; ++ks) {
            int ph = ((ks * 2 + h) ^ sw) * 8;
            bf16x8 af[2], bfr[2];
            #pragma unroll
            for (int i = 0; i < 2; ++i)
                af[i] = *(const bf16x8*)&As[(wm + i * 32 + l31) * BK + ph];
            #pragma unroll
            for (int j = 0; j < 2; ++j)
                bfr[j] = *(const bf16x8*)&Bs[(wn + j * 32 + l31) * BK + ph];
            #pragma unroll
            for (int i = 0; i < 2; ++i)
                #pragma unroll
                for (int j = 0; j < 2; ++j)
                    acc[i][j] = __builtin_amdgcn_mfma_f32_32x32x16_bf16(af[i], bfr[j], acc[i][j], 0, 0, 0);
        }
        __syncthreads();
    }

    #pragma unroll
    for (int i = 0; i < 2; ++i) {
        #pragma unroll
        for (int j = 0; j < 2; ++j) {
            int col = tn * 128 + wn + j * 32 + l31;
            float bias = ob[e * NO + col];
            #pragma unroll
            for (int r = 0; r < 16; ++r) {
                int row_d = (r & 3) + 8 * (r >> 2) + 4 * h;
                int m = tm * 128 + wm + i * 32 + row_d;
                if (m < count)
                    eo[(size_t)(off + m) * NO + col] = acc[i][j][r] + bias;
            }
        }
    }
}

// Residual GEMM + combine: 64x128 tile, wave = 1x2 blocks of 32x32.
// y[token] = x_bf . woutT + g0*eo[slot0] + g1*eo[slot1]   (single plain store)
__global__ __launch_bounds__(256) void gemm_res_kernel(
    const unsigned short* __restrict__ xb,   // [N][D] bf16
    const unsigned short* __restrict__ wt,   // [O][D] bf16
    const float* __restrict__ eo,            // [2N][O] fp32
    const int* __restrict__ invslot,         // [2N] token->slot
    const float* __restrict__ tok_g,         // [2N] gates
    float* __restrict__ y)                   // [N][O] fp32
{
    int tm = blockIdx.y, tn = blockIdx.x;
    __shared__ alignas(16) short As[64 * BK];
    __shared__ alignas(16) short Bs[128 * BK];

    int t = threadIdx.x;
    int c = t & 7, rl = t >> 3;
    int csw = (c ^ (rl & 7)) * 8;
    const unsigned short* aptr[2];
    const unsigned short* bptr[4];
    #pragma unroll
    for (int p = 0; p < 2; ++p)
        aptr[p] = xb + (size_t)(tm * 64 + p * 32 + rl) * DIM;
    #pragma unroll
    for (int p = 0; p < 4; ++p)
        bptr[p] = wt + (size_t)(tn * 128 + p * 32 + rl) * DIM;

    int lane = t & 63, wvi = t >> 6;
    int wm = (wvi & 1) * 32, wn = (wvi >> 1) * 64;
    int l31 = lane & 31, h = lane >> 5, sw = l31 & 7;

    f32x16 acc[2];
    #pragma unroll
    for (int j = 0; j < 2; ++j) acc[j] = (f32x16)(0.0f);

    for (int kt = 0; kt < DIM / BK; ++kt) {
        int kb = kt * BK + csw;
        #pragma unroll
        for (int p = 0; p < 2; ++p)
            async_copy16(aptr[p] + kb, (char*)As + p * 4096 + t * 16);
        #pragma unroll
        for (int p = 0; p < 4; ++p)
            async_copy16(bptr[p] + kb, (char*)Bs + p * 4096 + t * 16);
        __syncthreads();
        #pragma unroll
        for (int ks = 0; ks < 4; ++ks) {
            int ph = ((ks * 2 + h) ^ sw) * 8;
            bf16x8 af, bfr[2];
            af = *(const bf16x8*)&As[(wm + l31) * BK + ph];
            #pragma unroll
            for (int j = 0; j < 2; ++j)
                bfr[j] = *(const bf16x8*)&Bs[(wn + j * 32 + l31) * BK + ph];
            #pragma unroll
            for (int j = 0; j < 2; ++j)
                acc[j] = __builtin_amdgcn_mfma_f32_32x32x16_bf16(af, bfr[j], acc[j], 0, 0, 0);
        }
        __syncthreads();
    }

    #pragma unroll
    for (int r = 0; r < 16; ++r) {
        int row_d = (r & 3) + 8 * (r >> 2) + 4 * h;
        int row = tm * 64 + wm + row_d;
        int s0 = invslot[2 * row], s1 = invslot[2 * row + 1];
        float g0 = tok_g[2 * row], g1 = tok_g[2 * row + 1];
        #pragma unroll
        for (int j = 0; j < 2; ++j) {
            int col = tn * 128 + wn + j * 32 + l31;
            y[(size_t)row * NO + col] = acc[j][r]
                + g0 * eo[(size_t)s0 * NO + col]
                + g1 * eo[(size_t)s1 * NO + col];
        }
    }
}

extern "C" void kernel_launch(void* const* d_in, const int* in_sizes, int n_in,
                              void* d_out, int out_size, void* d_ws, size_t ws_size,
                              hipStream_t stream) {
    const float* x    = (const float*)d_in[0];
    const float* nw   = (const float*)d_in[6];
    const float* nb   = (const float*)d_in[7];
    const float* eps  = (const float*)d_in[8];
    const float* wg   = (const float*)d_in[9];
    const float* whw  = (const float*)d_in[10];
    const float* whb  = (const float*)d_in[11];
    const float* wow  = (const float*)d_in[12];
    const float* wob  = (const float*)d_in[13];
    const float* wout = (const float*)d_in[14];

    char* ws = (char*)d_ws;
    // workspace layout (bytes)
    unsigned short* xn_bf = (unsigned short*)(ws + 0);          //  8,388,608
    unsigned short* x_bf  = (unsigned short*)(ws + 8388608);    //  8,388,608
    unsigned short* wt_bf = (unsigned short*)(ws + 16777216);   //  2,097,152
    unsigned short* hbuf  = (unsigned short*)(ws + 18874368);   // 33,554,432
    float*          eo    = (float*)(ws + 52428800);            // 33,554,432
    char* meta = ws + 85983232;
    int*   counts     = (int*)(meta + 0);
    int*   offsets    = (int*)(meta + 128);
    int*   tok_e      = (int*)(meta + 2048);
    float* tok_g      = (float*)(meta + 2048 + 32768);
    int*   rowsbuf    = (int*)(meta + 2048 + 65536);
    int*   invslot    = (int*)(meta + 2048 + 98304);

    float* y = (float*)d_out;
    float* out_tail = y + (size_t)N_TOK * NO;   // loss, then gate_fraction[8]

    ln_gate_kernel<<<N_TOK, 256, 0, stream>>>(
        x, nw, nb, eps, wg, xn_bf, x_bf, tok_e, tok_g);
    routing_kernel<<<8 + 1024, 256, 0, stream>>>(
        tok_e, tok_g, counts, offsets, rowsbuf, invslot, out_tail, wout, wt_bf);
    gemm1_kernel<<<dim3(NH / 128, N_TOK / 128, NE), 256, 0, stream>>>(
        xn_bf, whw, whb, rowsbuf, counts, offsets, hbuf);
    gemm2_kernel<<<dim3(NO / 128, N_TOK / 128, NE), 256, 0, stream>>>(
        hbuf, wow, wob, counts, offsets, eo);
    gemm_res_kernel<<<dim3(NO / 128, N_TOK / 64), 256, 0, stream>>>(
        x_bf, wt_bf, eo, invslot, tok_g, y);
}

// Round 5
// 361.975 us; speedup vs baseline: 1.0845x; 1.0845x over previous
//
#include <hip/hip_runtime.h>
#include <hip/hip_bf16.h>
#include <stdint.h>

// Problem constants (from reference setup_inputs)
#define N_TOK 4096
#define DIM   1024
#define NE    8
#define NH    2048
#define NO    1024

typedef __attribute__((ext_vector_type(8))) short bf16x8;
typedef __attribute__((ext_vector_type(16))) float f32x16;

__device__ inline unsigned short f2bf(float f) {
    unsigned u = __float_as_uint(f);
    u += 0x7fffu + ((u >> 16) & 1u);   // round-to-nearest-even
    return (unsigned short)(u >> 16);
}

__device__ inline void async_copy16(const void* g, void* l) {
    __builtin_amdgcn_global_load_lds(
        (const __attribute__((address_space(1))) void*)g,
        (__attribute__((address_space(3))) void*)l, 16, 0, 0);
}

// ---------------- fused prep: LN+gating, weight cvt, transpose ----------------
// blocks [0, LN_BLK)                    : layernorm + gating logits (1 block/token)
// blocks [LN_BLK, LN_BLK+CVT_BLK)       : fp32->bf16 of wh and wo (one-shot,
//                                         1 float4/thread -- measured fastest form)
// blocks [LN_BLK+CVT_BLK, +1024)        : transpose+cvt of output_weight
#define LN_BLK  4096
#define CVT_BLK 32768
__global__ __launch_bounds__(256) void fused_prep_kernel(
    const float* __restrict__ x, const float* __restrict__ nw,
    const float* __restrict__ nb, const float* __restrict__ eps_p,
    const float* __restrict__ wg,
    unsigned short* __restrict__ xn_bf, unsigned short* __restrict__ x_bf,
    int* __restrict__ tok_e, float* __restrict__ tok_g,
    const float* __restrict__ whw, unsigned short* __restrict__ wh_bf,
    const float* __restrict__ wow, unsigned short* __restrict__ wo_bf,
    const float* __restrict__ wout, unsigned short* __restrict__ wt_bf)
{
    __shared__ float tile[32][33];
    __shared__ float rs[4], rs2[4];
    __shared__ float gred[4][NE];

    int b = blockIdx.x, t = threadIdx.x;

    if (b < LN_BLK) {
        // ---- layernorm + gating for token row b ----
        int n = b;
        int lane = t & 63, wv = t >> 6;

        const float4 xv = ((const float4*)(x + (size_t)n * DIM))[t];
        float s  = xv.x + xv.y + xv.z + xv.w;
        float s2 = xv.x*xv.x + xv.y*xv.y + xv.z*xv.z + xv.w*xv.w;
        #pragma unroll
        for (int o = 32; o > 0; o >>= 1) {
            s  += __shfl_down(s, o);
            s2 += __shfl_down(s2, o);
        }
        if (lane == 0) { rs[wv] = s; rs2[wv] = s2; }
        __syncthreads();
        float S  = rs[0] + rs[1] + rs[2] + rs[3];
        float S2 = rs2[0] + rs2[1] + rs2[2] + rs2[3];
        const float inv = 1.0f / (float)DIM;
        float mu = S * inv;
        float var = fmaxf(S2 * inv - mu * mu, 0.0f);   // biased, like F.layer_norm
        float rstd = rsqrtf(var + eps_p[0]);

        float4 w4 = ((const float4*)nw)[t];
        float4 b4 = ((const float4*)nb)[t];
        float xn0 = (xv.x - mu) * rstd * w4.x + b4.x;
        float xn1 = (xv.y - mu) * rstd * w4.y + b4.y;
        float xn2 = (xv.z - mu) * rstd * w4.z + b4.z;
        float xn3 = (xv.w - mu) * rstd * w4.w + b4.w;

        ushort4 pn; pn.x = f2bf(xn0); pn.y = f2bf(xn1); pn.z = f2bf(xn2); pn.w = f2bf(xn3);
        ((ushort4*)(xn_bf + (size_t)n * DIM))[t] = pn;
        ushort4 px; px.x = f2bf(xv.x); px.y = f2bf(xv.y); px.z = f2bf(xv.z); px.w = f2bf(xv.w);
        ((ushort4*)(x_bf + (size_t)n * DIM))[t] = px;

        // gating logits: x_norm (fp32) @ w_gate [D][E]
        float acc[NE];
        #pragma unroll
        for (int e = 0; e < NE; ++e) acc[e] = 0.0f;
        float xns[4] = {xn0, xn1, xn2, xn3};
        const float4* wgp = (const float4*)(wg + (size_t)(4 * t) * NE);
        #pragma unroll
        for (int j = 0; j < 4; ++j) {
            float4 w0 = wgp[2 * j], w1 = wgp[2 * j + 1];
            float xj = xns[j];
            acc[0] += xj * w0.x; acc[1] += xj * w0.y; acc[2] += xj * w0.z; acc[3] += xj * w0.w;
            acc[4] += xj * w1.x; acc[5] += xj * w1.y; acc[6] += xj * w1.z; acc[7] += xj * w1.w;
        }
        #pragma unroll
        for (int o = 32; o > 0; o >>= 1) {
            #pragma unroll
            for (int e = 0; e < NE; ++e) acc[e] += __shfl_down(acc[e], o);
        }
        if (lane == 0) {
            #pragma unroll
            for (int e = 0; e < NE; ++e) gred[wv][e] = acc[e];
        }
        __syncthreads();
        if (t == 0) {
            float lg[NE];
            float nrm2 = 0.0f;
            #pragma unroll
            for (int e = 0; e < NE; ++e) {
                lg[e] = gred[0][e] + gred[1][e] + gred[2][e] + gred[3][e];
                nrm2 += lg[e] * lg[e];
            }
            float den = fmaxf(sqrtf(nrm2), 1e-12f);
            float linv = 1.0f / den;
            #pragma unroll
            for (int e = 0; e < NE; ++e) lg[e] *= linv;
            float mx = lg[0];
            #pragma unroll
            for (int e = 1; e < NE; ++e) mx = fmaxf(mx, lg[e]);
            float p[NE], ps = 0.0f;
            #pragma unroll
            for (int e = 0; e < NE; ++e) { p[e] = expf(lg[e] - mx); ps += p[e]; }
            float pinv = 1.0f / ps;
            #pragma unroll
            for (int e = 0; e < NE; ++e) p[e] *= pinv;
            // top-2, lowest-index wins ties (jax.lax.top_k semantics)
            int i0 = 0; float b0 = lg[0];
            #pragma unroll
            for (int e = 1; e < NE; ++e) if (lg[e] > b0) { b0 = lg[e]; i0 = e; }
            int i1 = -1; float b1 = -3.0e38f;
            #pragma unroll
            for (int e = 0; e < NE; ++e) if (e != i0 && lg[e] > b1) { b1 = lg[e]; i1 = e; }
            tok_e[2 * n] = i0; tok_e[2 * n + 1] = i1;
            tok_g[2 * n] = p[i0]; tok_g[2 * n + 1] = p[i1];
        }
        return;
    }

    int b2 = b - LN_BLK;
    if (b2 < CVT_BLK) {
        // ---- bulk convert: 2 * 4,194,304 float4 groups ----
        const int n4each = NE * NH * DIM / 4;
        int i = b2 * 256 + t;
        const float4* s; ushort4* d; int j;
        if (i < n4each) { s = (const float4*)whw; d = (ushort4*)wh_bf; j = i; }
        else            { s = (const float4*)wow; d = (ushort4*)wo_bf; j = i - n4each; }
        float4 v = s[j];
        ushort4 o; o.x = f2bf(v.x); o.y = f2bf(v.y); o.z = f2bf(v.z); o.w = f2bf(v.w);
        d[j] = o;
        return;
    }

    // ---- output_weight [D][O] -> bf16 [O][D], 32x32 tile ----
    int idx = b2 - CVT_BLK;
    int o0 = (idx & 31) * 32, d0 = (idx >> 5) * 32;
    int tx = t & 31, ty0 = t >> 5;      // 32 x 8 threads, 4 rows each
    #pragma unroll
    for (int k = 0; k < 4; ++k) {
        int ty = ty0 + k * 8;
        tile[ty][tx] = wout[(size_t)(d0 + ty) * NO + o0 + tx];
    }
    __syncthreads();
    #pragma unroll
    for (int k = 0; k < 4; ++k) {
        int ty = ty0 + k * 8;
        wt_bf[(size_t)(o0 + ty) * DIM + d0 + tx] = f2bf(tile[tx][ty]);
    }
}

// ---------------- loss helper ----------------
__device__ inline float cv_sq(const float* v) {
    float m = 0.0f;
    for (int e = 0; e < NE; ++e) m += v[e];
    m *= (1.0f / NE);
    float s = 0.0f;
    for (int e = 0; e < NE; ++e) { float d = v[e] - m; s += d * d; }
    s *= (1.0f / (NE - 1));          // ddof=1
    return s / (m * m + 1e-6f);
}

// ---------------- routing: histogram/offsets/loss/scatter ----------------
// 8 blocks; block rb scatters chunk [rb*1024, rb*1024+1024). Blocks are
// independent (redundant histogram). Also emits the inverse map
// invslot[2*token+k] = slot for the combine epilogue in gemm_res.
__global__ __launch_bounds__(256) void routing_kernel(
    const int* __restrict__ tok_e, const float* __restrict__ tok_g,
    int* __restrict__ counts, int* __restrict__ offsets,
    int* __restrict__ rowsbuf, int* __restrict__ invslot,
    float* __restrict__ out_tail)
{
    __shared__ int   sc[4][NE], sp[4][NE];
    __shared__ float sf[4][NE];
    __shared__ int   lcur[NE];

    int rb = blockIdx.x, t = threadIdx.x;
    int lane = t & 63, wv = t >> 6;       // 4 waves
    int chunk0 = rb * 1024;

    int lc[NE]; float li[NE];
    #pragma unroll
    for (int e = 0; e < NE; ++e) { lc[e] = 0; li[e] = 0.0f; }
    int base = t * 32;
    #pragma unroll
    for (int q = 0; q < 8; ++q) {
        int4 e4 = *(const int4*)(tok_e + base + q * 4);
        float4 g4 = *(const float4*)(tok_g + base + q * 4);
        lc[e4.x]++; li[e4.x] += g4.x;
        lc[e4.y]++; li[e4.y] += g4.y;
        lc[e4.z]++; li[e4.z] += g4.z;
        lc[e4.w]++; li[e4.w] += g4.w;
    }
    int prior_flag = (base + 32 <= chunk0) ? 1 : 0;   // stripes don't straddle chunks
    int lp[NE];
    #pragma unroll
    for (int e = 0; e < NE; ++e) lp[e] = prior_flag ? lc[e] : 0;

    #pragma unroll
    for (int o = 32; o > 0; o >>= 1) {
        #pragma unroll
        for (int e = 0; e < NE; ++e) {
            lc[e] += __shfl_down(lc[e], o);
            lp[e] += __shfl_down(lp[e], o);
            li[e] += __shfl_down(li[e], o);
        }
    }
    if (lane == 0) {
        #pragma unroll
        for (int e = 0; e < NE; ++e) { sc[wv][e] = lc[e]; sp[wv][e] = lp[e]; sf[wv][e] = li[e]; }
    }
    __syncthreads();
    if (t == 0) {
        int cnt[NE], pri[NE]; float imp[NE];
        for (int e = 0; e < NE; ++e) {
            cnt[e] = sc[0][e] + sc[1][e] + sc[2][e] + sc[3][e];
            pri[e] = sp[0][e] + sp[1][e] + sp[2][e] + sp[3][e];
            imp[e] = sf[0][e] + sf[1][e] + sf[2][e] + sf[3][e];
        }
        int off = 0;
        for (int e = 0; e < NE; ++e) {
            lcur[e] = off + pri[e];
            if (rb == 0) { counts[e] = cnt[e]; offsets[e] = off; }
            off += cnt[e];
        }
        if (rb == 0) {
            float lcf[NE], lif[NE];
            for (int e = 0; e < NE; ++e) { lcf[e] = (float)cnt[e]; lif[e] = imp[e]; }
            float tot = (float)off;
            out_tail[0] = 0.01f * (cv_sq(lif) + cv_sq(lcf));              // loss
            for (int e = 0; e < NE; ++e) out_tail[1 + e] = lcf[e] / tot;  // gate_fraction
        }
    }
    __syncthreads();

    int g0 = chunk0 + 4 * t;
    int4 e4 = *(const int4*)(tok_e + g0);
    int s0 = atomicAdd(&lcur[e4.x], 1);
    int s1 = atomicAdd(&lcur[e4.y], 1);
    int s2 = atomicAdd(&lcur[e4.z], 1);
    int s3 = atomicAdd(&lcur[e4.w], 1);
    int tok0 = g0 >> 1;
    rowsbuf[s0] = tok0;     rowsbuf[s1] = tok0;
    rowsbuf[s2] = tok0 + 1; rowsbuf[s3] = tok0 + 1;
    invslot[g0]     = s0;   invslot[g0 + 1] = s1;
    invslot[g0 + 2] = s2;   invslot[g0 + 3] = s3;
}

// ---------------- GEMM kernels (32x32x16 MFMA) ----------------
// LDS layout: [row][64 shorts]; logical 16B-slot s of row r stored at physical
// slot s ^ (r & 7) -> bank-balanced wave64 ds_read_b128. Staging XORs the
// global source column; global_load_lds LDS dest stays lane-contiguous (m104).
// Fragments (32x32x16 bf16): A/B lane: row lane&31, k=(lane>>5)*8+j;
// C/D: col=lane&31, row=(reg&3)+8*(reg>>2)+4*(lane>>5)  [m74/m101].
//
// XCD swizzle (T1): dispatcher round-robins linear block id over 8 XCDs with
// private L2s. We remap (tm,tn) so each XCD (slice&7) owns a compact 2-D chunk
// of the tile space that fits its 4 MiB L2, instead of scattered tiles.
#define BK 64

// GEMM1: 128x128 tile, wave = 2x2 blocks of 32x32.
__global__ __launch_bounds__(256) void gemm1_kernel(
    const unsigned short* __restrict__ xn,   // [N][D] bf16
    const unsigned short* __restrict__ wh,   // [E][H][D] bf16
    const float* __restrict__ hb,            // [E][H]
    const int* __restrict__ rowsbuf,
    const int* __restrict__ counts, const int* __restrict__ offsets,
    unsigned short* __restrict__ hbuf)       // [2N][H] bf16
{
    int e = blockIdx.z;
    int count = counts[e];
    // XCD swizzle: gx=16, gy=32, nwg/slice=512. k=XCD phase, j=0..63.
    // XCD k owns chunk tm in [(k>>2)*4, +4), tn in [(k&3)*4, +4) for live j<16.
    // Bijective: tn&3=j&3, tn>>2=k&3, tm&3=(j>>2)&3, (tm>>2)&1=k>>2, tm>>3=j>>4.
    {
        int slice = blockIdx.y * 16 + blockIdx.x;
        int k = slice & 7, j = slice >> 3;
        int tn_ = (k & 3) * 4 + (j & 3);
        int tm_ = (k >> 2) * 4 + ((j >> 2) & 3) + (j >> 4) * 8;
        if (tm_ * 128 >= count) return;
        int off = offsets[e];
        int tm = tm_, tn = tn_;

        __shared__ alignas(16) short As[128 * BK];
        __shared__ alignas(16) short Bs[128 * BK];

        int t = threadIdx.x;
        int c = t & 7, rl = t >> 3;
        int csw = (c ^ (rl & 7)) * 8;            // swizzled source column (shorts)
        const unsigned short* aptr[4];
        const unsigned short* bptr[4];
        #pragma unroll
        for (int p = 0; p < 4; ++p) {
            int mrow = tm * 128 + p * 32 + rl;
            int mc = mrow < count ? mrow : count - 1;
            int token = rowsbuf[off + mc];
            aptr[p] = xn + (size_t)token * DIM;
            bptr[p] = wh + ((size_t)e * NH + tn * 128 + p * 32 + rl) * DIM;
        }

        int lane = t & 63, wvi = t >> 6;
        int wm = (wvi & 1) * 64, wn = (wvi >> 1) * 64;
        int l31 = lane & 31, h = lane >> 5, sw = l31 & 7;

        f32x16 acc[2][2];
        #pragma unroll
        for (int i = 0; i < 2; ++i)
            #pragma unroll
            for (int j2 = 0; j2 < 2; ++j2) acc[i][j2] = (f32x16)(0.0f);

        for (int kt = 0; kt < DIM / BK; ++kt) {
            int kb = kt * BK + csw;
            #pragma unroll
            for (int p = 0; p < 4; ++p)
                async_copy16(aptr[p] + kb, (char*)As + p * 4096 + t * 16);
            #pragma unroll
            for (int p = 0; p < 4; ++p)
                async_copy16(bptr[p] + kb, (char*)Bs + p * 4096 + t * 16);
            __syncthreads();
            #pragma unroll
            for (int ks = 0; ks < 4; ++ks) {
                int ph = ((ks * 2 + h) ^ sw) * 8;
                bf16x8 af[2], bfr[2];
                #pragma unroll
                for (int i = 0; i < 2; ++i)
                    af[i] = *(const bf16x8*)&As[(wm + i * 32 + l31) * BK + ph];
                #pragma unroll
                for (int j2 = 0; j2 < 2; ++j2)
                    bfr[j2] = *(const bf16x8*)&Bs[(wn + j2 * 32 + l31) * BK + ph];
                #pragma unroll
                for (int i = 0; i < 2; ++i)
                    #pragma unroll
                    for (int j2 = 0; j2 < 2; ++j2)
                        acc[i][j2] = __builtin_amdgcn_mfma_f32_32x32x16_bf16(af[i], bfr[j2], acc[i][j2], 0, 0, 0);
            }
            __syncthreads();
        }

        #pragma unroll
        for (int i = 0; i < 2; ++i) {
            #pragma unroll
            for (int j2 = 0; j2 < 2; ++j2) {
                int col = tn * 128 + wn + j2 * 32 + l31;
                float bias = hb[e * NH + col];
                #pragma unroll
                for (int r = 0; r < 16; ++r) {
                    int row_d = (r & 3) + 8 * (r >> 2) + 4 * h;
                    int m = tm * 128 + wm + i * 32 + row_d;
                    if (m < count) {
                        float v = acc[i][j2][r] + bias;
                        v = v / (1.0f + __expf(-v));           // silu
                        hbuf[(size_t)(off + m) * NH + col] = f2bf(v);
                    }
                }
            }
        }
    }
}

// GEMM2: 128x128 tile, wave = 2x2 blocks of 32x32 (same structure as gemm1).
// Epilogue: plain fp32 store of (acc + bias) into eo[slot][col] — NO atomics.
// The gated combine into y happens in gemm_res_kernel's epilogue.
__global__ __launch_bounds__(256) void gemm2_kernel(
    const unsigned short* __restrict__ hbuf,  // [2N][H] bf16
    const unsigned short* __restrict__ wo,    // [E][O][H] bf16
    const float* __restrict__ ob,             // [E][O]
    const int* __restrict__ counts, const int* __restrict__ offsets,
    float* __restrict__ eo)                   // [2N][O] fp32, slot-indexed
{
    int e = blockIdx.z;
    int count = counts[e];
    // XCD swizzle: gx=8, gy=32, nwg/slice=256. XCD k owns chunk
    // tm in [(k>>2)*4, +4), tn in [(k&3)*2, +2) for live j<8. Bijective:
    // tn&1=j&1, tn>>1=k&3, tm&3=(j>>1)&3, (tm>>2)&1=k>>2, tm>>3=j>>3.
    int slice = blockIdx.y * 8 + blockIdx.x;
    int k = slice & 7, j = slice >> 3;
    int tn = (k & 3) * 2 + (j & 1);
    int tm = (k >> 2) * 4 + ((j >> 1) & 3) + (j >> 3) * 8;
    if (tm * 128 >= count) return;
    int off = offsets[e];

    __shared__ alignas(16) short As[128 * BK];
    __shared__ alignas(16) short Bs[128 * BK];

    int t = threadIdx.x;
    int c = t & 7, rl = t >> 3;
    int csw = (c ^ (rl & 7)) * 8;
    const unsigned short* aptr[4];
    const unsigned short* bptr[4];
    #pragma unroll
    for (int p = 0; p < 4; ++p) {
        int mrow = tm * 128 + p * 32 + rl;
        int mc = mrow < count ? mrow : count - 1;
        aptr[p] = hbuf + (size_t)(off + mc) * NH;
        bptr[p] = wo + ((size_t)e * NO + tn * 128 + p * 32 + rl) * NH;
    }

    int lane = t & 63, wvi = t >> 6;
    int wm = (wvi & 1) * 64, wn = (wvi >> 1) * 64;
    int l31 = lane & 31, h = lane >> 5, sw = l31 & 7;

    f32x16 acc[2][2];
    #pragma unroll
    for (int i = 0; i < 2; ++i)
        #pragma unroll
        for (int j2 = 0; j2 < 2; ++j2) acc[i][j2] = (f32x16)(0.0f);

    for (int kt = 0; kt < NH / BK; ++kt) {
        int kb = kt * BK + csw;
        #pragma unroll
        for (int p = 0; p < 4; ++p)
            async_copy16(aptr[p] + kb, (char*)As + p * 4096 + t * 16);
        #pragma unroll
        for (int p = 0; p < 4; ++p)
            async_copy16(bptr[p] + kb, (char*)Bs + p * 4096 + t * 16);
        __syncthreads();
        #pragma unroll
        for (int ks = 0; ks < 4; ++ks) {
            int ph = ((ks * 2 + h) ^ sw) * 8;
            bf16x8 af[2], bfr[2];
            #pragma unroll
            for (int i = 0; i < 2; ++i)
                af[i] = *(const bf16x8*)&As[(wm + i * 32 + l31) * BK + ph];
            #pragma unroll
            for (int j2 = 0; j2 < 2; ++j2)
                bfr[j2] = *(const bf16x8*)&Bs[(wn + j2 * 32 + l31) * BK + ph];
            #pragma unroll
            for (int i = 0; i < 2; ++i)
                #pragma unroll
                for (int j2 = 0; j2 < 2; ++j2)
                    acc[i][j2] = __builtin_amdgcn_mfma_f32_32x32x16_bf16(af[i], bfr[j2], acc[i][j2], 0, 0, 0);
        }
        __syncthreads();
    }

    #pragma unroll
    for (int i = 0; i < 2; ++i) {
        #pragma unroll
        for (int j2 = 0; j2 < 2; ++j2) {
            int col = tn * 128 + wn + j2 * 32 + l31;
            float bias = ob[e * NO + col];
            #pragma unroll
            for (int r = 0; r < 16; ++r) {
                int row_d = (r & 3) + 8 * (r >> 2) + 4 * h;
                int m = tm * 128 + wm + i * 32 + row_d;
                if (m < count)
                    eo[(size_t)(off + m) * NO + col] = acc[i][j2][r] + bias;
            }
        }
    }
}

// Residual GEMM + combine: 64x128 tile, wave = 1x2 blocks of 32x32.
// y[token] = x_bf . woutT + g0*eo[slot0] + g1*eo[slot1]   (single plain store)
__global__ __launch_bounds__(256) void gemm_res_kernel(
    const unsigned short* __restrict__ xb,   // [N][D] bf16
    const unsigned short* __restrict__ wt,   // [O][D] bf16
    const float* __restrict__ eo,            // [2N][O] fp32
    const int* __restrict__ invslot,         // [2N] token->slot
    const float* __restrict__ tok_g,         // [2N] gates
    float* __restrict__ y)                   // [N][O] fp32
{
    // XCD swizzle: gx=8, gy=64, nwg=512. XCD k owns chunk
    // tm in [(k>>1)*16, +16), tn in [(k&1)*4, +4). Bijective:
    // tn = (k&1)*4 + (j&3), tm = (k>>1)*16 + (j>>2), j in [0,64).
    int slice = blockIdx.y * 8 + blockIdx.x;
    int k = slice & 7, j = slice >> 3;
    int tn = (k & 1) * 4 + (j & 3);
    int tm = (k >> 1) * 16 + (j >> 2);

    __shared__ alignas(16) short As[64 * BK];
    __shared__ alignas(16) short Bs[128 * BK];

    int t = threadIdx.x;
    int c = t & 7, rl = t >> 3;
    int csw = (c ^ (rl & 7)) * 8;
    const unsigned short* aptr[2];
    const unsigned short* bptr[4];
    #pragma unroll
    for (int p = 0; p < 2; ++p)
        aptr[p] = xb + (size_t)(tm * 64 + p * 32 + rl) * DIM;
    #pragma unroll
    for (int p = 0; p < 4; ++p)
        bptr[p] = wt + (size_t)(tn * 128 + p * 32 + rl) * DIM;

    int lane = t & 63, wvi = t >> 6;
    int wm = (wvi & 1) * 32, wn = (wvi >> 1) * 64;
    int l31 = lane & 31, h = lane >> 5, sw = l31 & 7;

    f32x16 acc[2];
    #pragma unroll
    for (int j2 = 0; j2 < 2; ++j2) acc[j2] = (f32x16)(0.0f);

    for (int kt = 0; kt < DIM / BK; ++kt) {
        int kb = kt * BK + csw;
        #pragma unroll
        for (int p = 0; p < 2; ++p)
            async_copy16(aptr[p] + kb, (char*)As + p * 4096 + t * 16);
        #pragma unroll
        for (int p = 0; p < 4; ++p)
            async_copy16(bptr[p] + kb, (char*)Bs + p * 4096 + t * 16);
        __syncthreads();
        #pragma unroll
        for (int ks = 0; ks < 4; ++ks) {
            int ph = ((ks * 2 + h) ^ sw) * 8;
            bf16x8 af, bfr[2];
            af = *(const bf16x8*)&As[(wm + l31) * BK + ph];
            #pragma unroll
            for (int j2 = 0; j2 < 2; ++j2)
                bfr[j2] = *(const bf16x8*)&Bs[(wn + j2 * 32 + l31) * BK + ph];
            #pragma unroll
            for (int j2 = 0; j2 < 2; ++j2)
                acc[j2] = __builtin_amdgcn_mfma_f32_32x32x16_bf16(af, bfr[j2], acc[j2], 0, 0, 0);
        }
        __syncthreads();
    }

    #pragma unroll
    for (int r = 0; r < 16; ++r) {
        int row_d = (r & 3) + 8 * (r >> 2) + 4 * h;
        int row = tm * 64 + wm + row_d;
        int s0 = invslot[2 * row], s1 = invslot[2 * row + 1];
        float g0 = tok_g[2 * row], g1 = tok_g[2 * row + 1];
        #pragma unroll
        for (int j2 = 0; j2 < 2; ++j2) {
            int col = tn * 128 + wn + j2 * 32 + l31;
            y[(size_t)row * NO + col] = acc[j2][r]
                + g0 * eo[(size_t)s0 * NO + col]
                + g1 * eo[(size_t)s1 * NO + col];
        }
    }
}

extern "C" void kernel_launch(void* const* d_in, const int* in_sizes, int n_in,
                              void* d_out, int out_size, void* d_ws, size_t ws_size,
                              hipStream_t stream) {
    const float* x    = (const float*)d_in[0];
    const float* nw   = (const float*)d_in[6];
    const float* nb   = (const float*)d_in[7];
    const float* eps  = (const float*)d_in[8];
    const float* wg   = (const float*)d_in[9];
    const float* whw  = (const float*)d_in[10];
    const float* whb  = (const float*)d_in[11];
    const float* wow  = (const float*)d_in[12];
    const float* wob  = (const float*)d_in[13];
    const float* wout = (const float*)d_in[14];

    char* ws = (char*)d_ws;
    // workspace layout (bytes)
    unsigned short* xn_bf = (unsigned short*)(ws + 0);          //  8,388,608
    unsigned short* x_bf  = (unsigned short*)(ws + 8388608);    //  8,388,608
    unsigned short* wh_bf = (unsigned short*)(ws + 16777216);   // 33,554,432
    unsigned short* wo_bf = (unsigned short*)(ws + 50331648);   // 33,554,432
    unsigned short* wt_bf = (unsigned short*)(ws + 83886080);   //  2,097,152
    unsigned short* hbuf  = (unsigned short*)(ws + 85983232);   // 33,554,432
    // eo [2N][O] fp32 (33,554,432 B) aliases wh_bf: wh_bf is dead after gemm1,
    // eo is written by gemm2 which is stream-ordered after gemm1.
    float* eo = (float*)(ws + 16777216);
    char* meta = ws + 119537664;
    int*   counts     = (int*)(meta + 0);
    int*   offsets    = (int*)(meta + 128);
    int*   tok_e      = (int*)(meta + 2048);
    float* tok_g      = (float*)(meta + 2048 + 32768);
    int*   rowsbuf    = (int*)(meta + 2048 + 65536);
    int*   invslot    = (int*)(meta + 2048 + 98304);

    float* y = (float*)d_out;
    float* out_tail = y + (size_t)N_TOK * NO;   // loss, then gate_fraction[8]

    fused_prep_kernel<<<LN_BLK + CVT_BLK + 1024, 256, 0, stream>>>(
        x, nw, nb, eps, wg, xn_bf, x_bf, tok_e, tok_g,
        whw, wh_bf, wow, wo_bf, wout, wt_bf);
    routing_kernel<<<8, 256, 0, stream>>>(
        tok_e, tok_g, counts, offsets, rowsbuf, invslot, out_tail);
    gemm1_kernel<<<dim3(NH / 128, N_TOK / 128, NE), 256, 0, stream>>>(
        xn_bf, wh_bf, whb, rowsbuf, counts, offsets, hbuf);
    gemm2_kernel<<<dim3(NO / 128, N_TOK / 128, NE), 256, 0, stream>>>(
        hbuf, wo_bf, wob, counts, offsets, eo);
    gemm_res_kernel<<<dim3(NO / 128, N_TOK / 64), 256, 0, stream>>>(
        x_bf, wt_bf, eo, invslot, tok_g, y);
}